// Round 2
// baseline (313.799 us; speedup 1.0000x reference)
//
#include <hip/hip_runtime.h>

// Problem constants (match reference)
constexpr int NUM_LUT = 3;
constexpr int IN_F    = 4096;
constexpr int OUT_F   = 4096;
constexpr int VEC     = 4;
constexpr int LUT     = 16;
constexpr int GROUP   = 128;
constexpr int G       = IN_F / VEC;    // 1024 vector-groups
constexpr int NG      = IN_F / GROUP;  // 32 quant groups

// Native vector type — __builtin_nontemporal_load requires this, not HIP_vector_type
typedef float f32x4 __attribute__((ext_vector_type(4)));

// Tile: each block handles GT g-values x OT o-values
constexpr int GT    = 4;
constexpr int OT    = 64;
constexpr int BLOCK = GT * OT;  // 256 threads

__global__ __launch_bounds__(BLOCK) void recon_kernel(
    const float* __restrict__ gate,      // [3, 1024, 4096, 16]
    const float* __restrict__ codebook,  // [3, 1024, 16, 4]
    const float* __restrict__ scales,    // [4096, 32]
    const int*   __restrict__ zeros,     // [4096, 32]
    float* __restrict__ out)             // [4096, 4096]
{
    // Codebook slice for this block's 4 g-values: 3 * 4 * 16 float4 = 3 KB
    __shared__ f32x4 cb[NUM_LUT * GT * LUT];

    const int t  = threadIdx.x;
    const int g0 = blockIdx.x * GT;
    const int o0 = blockIdx.y * OT;

    // Stage codebook into LDS (192 float4 loads, threads 0..191)
    if (t < NUM_LUT * GT * LUT) {
        const int l   = t >> 6;        // / (GT*LUT)
        const int rem = t & 63;
        const int gl  = rem >> 4;      // / LUT
        const int s   = rem & 15;
        cb[t] = reinterpret_cast<const f32x4*>(codebook)[(l * G + g0 + gl) * LUT + s];
    }
    __syncthreads();

    const int gl = t & (GT - 1);       // lane's g within tile
    const int g  = g0 + gl;
    const int o  = o0 + (t >> 2);      // lane's output row

    f32x4 acc = {0.f, 0.f, 0.f, 0.f};
    #pragma unroll
    for (int l = 0; l < NUM_LUT; ++l) {
        const f32x4* gp = reinterpret_cast<const f32x4*>(
            gate + ((size_t)(l * G + g) * OUT_F + o) * LUT);
        // 64 B of gate logits for this (l, g, o): 4x dwordx4, streaming
        f32x4 q0 = __builtin_nontemporal_load(gp + 0);
        f32x4 q1 = __builtin_nontemporal_load(gp + 1);
        f32x4 q2 = __builtin_nontemporal_load(gp + 2);
        f32x4 q3 = __builtin_nontemporal_load(gp + 3);

        float v[16] = {q0.x, q0.y, q0.z, q0.w,  q1.x, q1.y, q1.z, q1.w,
                       q2.x, q2.y, q2.z, q2.w,  q3.x, q3.y, q3.z, q3.w};

        // First-occurrence argmax (strict > matches jnp.argmax tie-break)
        int   best = 0;
        float bv   = v[0];
        #pragma unroll
        for (int s = 1; s < LUT; ++s) {
            if (v[s] > bv) { bv = v[s]; best = s; }
        }

        const f32x4 w = cb[(l * GT + gl) * LUT + best];
        acc += w;
    }

    // Dequantize: ng = (g*4)/128 = g >> 5
    const int   ng = g >> 5;
    const float sc = scales[o * NG + ng];
    const float zp = (float)zeros[o * NG + ng];

    f32x4 r = (acc - zp) * sc;

    // Lanes 4k..4k+3 write 16 consecutive floats of row o -> full 64B lines
    reinterpret_cast<f32x4*>(out)[(size_t)o * (IN_F / 4) + g] = r;
}

extern "C" void kernel_launch(void* const* d_in, const int* in_sizes, int n_in,
                              void* d_out, int out_size, void* d_ws, size_t ws_size,
                              hipStream_t stream) {
    const float* gate     = (const float*)d_in[0];
    const float* codebook = (const float*)d_in[1];
    const float* scales   = (const float*)d_in[2];
    const int*   zeros    = (const int*)d_in[3];
    float*       out      = (float*)d_out;

    dim3 grid(G / GT, OUT_F / OT);  // (256, 64) = 16384 blocks
    recon_kernel<<<grid, BLOCK, 0, stream>>>(gate, codebook, scales, zeros, out);
}

// Round 3
// 201.215 us; speedup vs baseline: 1.5595x; 1.5595x over previous
//
#include <hip/hip_runtime.h>

// Problem constants (match reference)
constexpr int NUM_LUT = 3;
constexpr int IN_F    = 4096;
constexpr int OUT_F   = 4096;
constexpr int VEC     = 4;
constexpr int LUT     = 16;
constexpr int GROUP   = 128;
constexpr int G       = IN_F / VEC;    // 1024 vector-groups
constexpr int NG      = IN_F / GROUP;  // 32 quant groups

typedef float f32x4 __attribute__((ext_vector_type(4)));

// Tile: each block handles GT g-values x OT o-values
constexpr int GT    = 4;
constexpr int OT    = 64;
constexpr int BLOCK = GT * OT;  // 256 threads

__global__ __launch_bounds__(BLOCK) void recon_kernel(
    const float* __restrict__ gate,      // [3, 1024, 4096, 16]
    const float* __restrict__ codebook,  // [3, 1024, 16, 4]
    const float* __restrict__ scales,    // [4096, 32]
    const int*   __restrict__ zeros,     // [4096, 32]
    float* __restrict__ out)             // [4096, 4096]
{
    // Codebook slice for this block's 4 g-values: 3 * 4 * 16 float4 = 3 KB
    __shared__ f32x4 cb[NUM_LUT * GT * LUT];

    const int t  = threadIdx.x;
    const int g0 = blockIdx.x * GT;
    const int o0 = blockIdx.y * OT;

    // Stage codebook into LDS (192 float4 loads, threads 0..191)
    if (t < NUM_LUT * GT * LUT) {
        const int l   = t >> 6;        // / (GT*LUT)
        const int rem = t & 63;
        const int gl  = rem >> 4;      // / LUT
        const int s   = rem & 15;
        cb[t] = reinterpret_cast<const f32x4*>(codebook)[(l * G + g0 + gl) * LUT + s];
    }
    __syncthreads();

    const int gl = t & (GT - 1);       // lane's g within tile
    const int g  = g0 + gl;
    const int o  = o0 + (t >> 2);      // lane's output row

    // Issue ALL 12 gate loads first (192 B/thread in flight) — cached loads:
    // each 64B line is read by one thread as 4x dwordx4; L1 serves loads 2-4.
    f32x4 q[NUM_LUT][4];
    #pragma unroll
    for (int l = 0; l < NUM_LUT; ++l) {
        const f32x4* gp = reinterpret_cast<const f32x4*>(
            gate + ((size_t)(l * G + g) * OUT_F + o) * LUT);
        q[l][0] = gp[0];
        q[l][1] = gp[1];
        q[l][2] = gp[2];
        q[l][3] = gp[3];
    }

    f32x4 acc = {0.f, 0.f, 0.f, 0.f};
    #pragma unroll
    for (int l = 0; l < NUM_LUT; ++l) {
        float v[16];
        #pragma unroll
        for (int c = 0; c < 4; ++c) {
            v[4 * c + 0] = q[l][c].x;
            v[4 * c + 1] = q[l][c].y;
            v[4 * c + 2] = q[l][c].z;
            v[4 * c + 3] = q[l][c].w;
        }

        // First-occurrence argmax (strict > matches jnp.argmax tie-break)
        int   best = 0;
        float bv   = v[0];
        #pragma unroll
        for (int s = 1; s < LUT; ++s) {
            if (v[s] > bv) { bv = v[s]; best = s; }
        }

        acc += cb[(l * GT + gl) * LUT + best];
    }

    // Dequantize: ng = (g*4)/128 = g >> 5
    const int   ng = g >> 5;
    const float sc = scales[o * NG + ng];
    const float zp = (float)zeros[o * NG + ng];

    f32x4 r = (acc - zp) * sc;

    // Lanes 4k..4k+3 write 16 consecutive floats of row o -> full 64B lines
    reinterpret_cast<f32x4*>(out)[(size_t)o * (IN_F / 4) + g] = r;
}

extern "C" void kernel_launch(void* const* d_in, const int* in_sizes, int n_in,
                              void* d_out, int out_size, void* d_ws, size_t ws_size,
                              hipStream_t stream) {
    const float* gate     = (const float*)d_in[0];
    const float* codebook = (const float*)d_in[1];
    const float* scales   = (const float*)d_in[2];
    const int*   zeros    = (const int*)d_in[3];
    float*       out      = (float*)d_out;

    dim3 grid(G / GT, OUT_F / OT);  // (256, 64) = 16384 blocks
    recon_kernel<<<grid, BLOCK, 0, stream>>>(gate, codebook, scales, zeros, out);
}

// Round 4
// 180.106 us; speedup vs baseline: 1.7423x; 1.1172x over previous
//
#include <hip/hip_runtime.h>

// Problem constants (match reference)
constexpr int NUM_LUT = 3;
constexpr int IN_F    = 4096;
constexpr int OUT_F   = 4096;
constexpr int VEC     = 4;
constexpr int LUT     = 16;
constexpr int GROUP   = 128;
constexpr int G       = IN_F / VEC;    // 1024 vector-groups
constexpr int NG      = IN_F / GROUP;  // 32 quant groups

typedef float f32x4 __attribute__((ext_vector_type(4)));

// 4 lanes per (g,o) pair. Wave = one g x 16 o. Block = 4 waves = 4 g x 16 o.
constexpr int GT    = 4;   // g per block (one per wave)
constexpr int OT    = 16;  // o per block
constexpr int BLOCK = 256;

__global__ __launch_bounds__(BLOCK) void recon_kernel(
    const float* __restrict__ gate,      // [3, 1024, 4096, 16]
    const float* __restrict__ codebook,  // [3, 1024, 16, 4]
    const float* __restrict__ scales,    // [4096, 32]
    const int*   __restrict__ zeros,     // [4096, 32]
    float* __restrict__ out)             // [4096, 4096]
{
    __shared__ __align__(16) float cb[NUM_LUT * GT * LUT * VEC]; // 3 KB
    __shared__ float sred[OT][GT * VEC + 1];                     // 16 x 17 floats (pad)

    const int t    = threadIdx.x;
    const int w    = t >> 6;      // wave id = local g
    const int lane = t & 63;
    const int grp  = lane >> 2;   // 4-lane group = local o
    const int c    = lane & 3;    // which 16B chunk of the 64B gate row

    const int g0 = blockIdx.x * GT;
    const int o0 = blockIdx.y * OT;
    const int g  = g0 + w;
    const int o  = o0 + grp;

    // Stage codebook slice: 192 float4 (threads 0..191)
    if (t < NUM_LUT * GT * LUT) {
        const int l = t >> 6, rem = t & 63, gl = rem >> 4, s = rem & 15;
        reinterpret_cast<f32x4*>(cb)[t] =
            reinterpret_cast<const f32x4*>(codebook)[(l * G + g0 + gl) * LUT + s];
    }
    __syncthreads();

    // Gate loads: offset from tile base = (grp*16 + c*4) floats = lane*16 B.
    // One instruction = 64 lanes x 16B fully contiguous (1 KB). Issue all 3 up front.
    f32x4 q[NUM_LUT];
    #pragma unroll
    for (int l = 0; l < NUM_LUT; ++l) {
        const float* gp = gate + ((size_t)(l * G + g) * OUT_F + o0) * LUT;
        q[l] = *reinterpret_cast<const f32x4*>(gp + lane * 4);
    }

    float acc = 0.f;
    #pragma unroll
    for (int l = 0; l < NUM_LUT; ++l) {
        // Local argmax over this lane's 4 candidates (global idx c*4+j),
        // strict > keeps the first occurrence.
        float bv = q[l].x; int bi = c * 4;
        if (q[l].y > bv) { bv = q[l].y; bi = c * 4 + 1; }
        if (q[l].z > bv) { bv = q[l].z; bi = c * 4 + 2; }
        if (q[l].w > bv) { bv = q[l].w; bi = c * 4 + 3; }
        // Merge across the 4-lane group (quad-perm shuffles); on ties prefer
        // the lower index = jnp.argmax first-occurrence semantics.
        #pragma unroll
        for (int m = 1; m <= 2; m <<= 1) {
            float ov = __shfl_xor(bv, m, 64);
            int   oi = __shfl_xor(bi, m, 64);
            if (ov > bv || (ov == bv && oi < bi)) { bv = ov; bi = oi; }
        }
        // Each lane accumulates its own component c of the chosen codeword.
        acc += cb[((l * GT + w) * LUT + bi) * VEC + c];
    }

    // Dequantize: column = g*4+c; ng = (g*4)/128 = g>>5 (same for c=0..3)
    const int   ng = g >> 5;
    const float sc = scales[o * NG + ng];
    const float zp = (float)zeros[o * NG + ng];
    const float r  = (acc - zp) * sc;

    // Transpose through LDS so stores are 64B-contiguous per output row.
    sred[grp][w * VEC + c] = r;
    __syncthreads();

    if (t < 64) {
        const int row = t >> 2, ch = t & 3;
        f32x4 v;
        v.x = sred[row][ch * 4 + 0];
        v.y = sred[row][ch * 4 + 1];
        v.z = sred[row][ch * 4 + 2];
        v.w = sred[row][ch * 4 + 3];
        *reinterpret_cast<f32x4*>(out + (size_t)(o0 + row) * IN_F + g0 * VEC + ch * 4) = v;
    }
}

extern "C" void kernel_launch(void* const* d_in, const int* in_sizes, int n_in,
                              void* d_out, int out_size, void* d_ws, size_t ws_size,
                              hipStream_t stream) {
    const float* gate     = (const float*)d_in[0];
    const float* codebook = (const float*)d_in[1];
    const float* scales   = (const float*)d_in[2];
    const int*   zeros    = (const int*)d_in[3];
    float*       out      = (float*)d_out;

    dim3 grid(G / GT, OUT_F / OT);  // (256, 256) = 65536 blocks
    recon_kernel<<<grid, BLOCK, 0, stream>>>(gate, codebook, scales, zeros, out);
}